// Round 1
// baseline (106.497 us; speedup 1.0000x reference)
//
#include <hip/hip_runtime.h>

#define B_SZ 8
#define T_SZ 4096
#define D_SZ 1024
#define N_SZ 128
#define M_SZ (B_SZ*T_SZ)          // 32768
#define CHUNK 64                  // scan chunk length
#define NCHUNK (T_SZ/CHUNK)       // 64

typedef __attribute__((ext_vector_type(8))) __bf16 bf16x8;
typedef __attribute__((ext_vector_type(4))) float f32x4;
typedef __attribute__((ext_vector_type(4))) unsigned int u32x4;
typedef __attribute__((ext_vector_type(4))) float fvec4;

static __device__ __forceinline__ unsigned short f2bf(float f){
  union { float f; unsigned int u; } v; v.f = f;
  unsigned int r = v.u + 0x7fffu + ((v.u >> 16) & 1u);
  return (unsigned short)(r >> 16);
}

static __device__ __forceinline__ void cp16(const void* g, void* l){
  __builtin_amdgcn_global_load_lds(
      (const __attribute__((address_space(1))) void*)g,
      (__attribute__((address_space(3))) void*)l, 16, 0, 0);
}

static __device__ __forceinline__ f32x4 zero4(){
  f32x4 v = {0.f, 0.f, 0.f, 0.f};
  return v;
}

// ---------------------------------------------------------------------------
// K0: convert weights to bf16, pre-swizzled so GEMM tiles are contiguous
// global_load_lds images.
// bw: [16 kchunks][128 n][64 k] bf16; byte = c*16384 + n*128 + ((kk*2)^((n&7)<<4))
// cw: [8 dchunks][128 d][128 k] bf16; byte = c*32768 + dd*256 + ((k*2)^((dd&15)<<4))
// ---------------------------------------------------------------------------
__global__ __launch_bounds__(256) void k_conv(const float* __restrict__ Bw,
                                              const float* __restrict__ Cw,
                                              unsigned short* __restrict__ bw,
                                              unsigned short* __restrict__ cw){
  int t = blockIdx.x*256 + threadIdx.x;   // 131072 threads total
  {
    int n = t >> 10, k = t & 1023;
    int c = k >> 6, kk = k & 63;
    unsigned byte = (unsigned)c*16384u + (unsigned)n*128u
                  + (unsigned)((kk*2) ^ ((n&7)<<4));
    bw[byte>>1] = f2bf(Bw[n*1024 + k]);
  }
  {
    int d = t >> 7, k = t & 127;
    int c = d >> 7, dd = d & 127;
    unsigned byte = (unsigned)c*32768u + (unsigned)dd*256u
                  + (unsigned)((k*2) ^ ((dd&15)<<4));
    cw[byte>>1] = f2bf(Cw[d*128 + k]);
  }
}

// ---------------------------------------------------------------------------
// GEMM1: Bu[m][n] = (sum_k u[m][k]*B_w[n][k] + B_b[n]) * dt[n]
// M=32768 (BM=64/block), N=128 (full), K=1024 (BK=64)
// ---------------------------------------------------------------------------
__global__ __launch_bounds__(256) void k_gemm1(const float* __restrict__ u,
                                               const unsigned short* __restrict__ bw,
                                               const float* __restrict__ Bb,
                                               const float* __restrict__ logdt,
                                               float* __restrict__ Bu){
  __shared__ __align__(16) unsigned short lA[64*64];    // 8 KB, swizzled [row][k]
  __shared__ __align__(16) unsigned short lB[128*64];   // 16 KB, swizzled [n][k]
  const int tid  = threadIdx.x;
  const int lane = tid & 63;
  const int wave = tid >> 6;
  const int m0   = blockIdx.x * 64;
  const int l15  = lane & 15;
  const int lhi  = lane >> 4;

  f32x4 acc[8];
  #pragma unroll
  for (int i=0;i<8;++i) acc[i] = zero4();

  for (int kc=0; kc<16; ++kc){
    // stage B_w k-chunk: 16KB contiguous (pre-swizzled) via global_load_lds
    #pragma unroll
    for (int rep=0; rep<4; ++rep){
      const char* g = (const char*)bw + kc*16384 + rep*4096 + wave*1024 + lane*16;
      char* l = (char*)lB + rep*4096 + wave*1024;
      cp16(g, l);
    }
    // stage u tile: fp32 -> bf16, swizzled ds_write
    #pragma unroll
    for (int rep=0; rep<2; ++rep){
      int q = rep*256 + tid;            // 0..511
      int row = q >> 3, ks = q & 7;
      const float* src = u + (size_t)(m0+row)*1024 + kc*64 + ks*8;
      fvec4 f0 = *(const fvec4*)src;
      fvec4 f1 = *(const fvec4*)(src+4);
      u32x4 p;
      p.x = (unsigned)f2bf(f0.x) | ((unsigned)f2bf(f0.y)<<16);
      p.y = (unsigned)f2bf(f0.z) | ((unsigned)f2bf(f0.w)<<16);
      p.z = (unsigned)f2bf(f1.x) | ((unsigned)f2bf(f1.y)<<16);
      p.w = (unsigned)f2bf(f1.z) | ((unsigned)f2bf(f1.w)<<16);
      unsigned byte = (unsigned)row*128u + (unsigned)((ks*16) ^ ((row&7)<<4));
      *(u32x4*)((char*)lA + byte) = p;
    }
    __syncthreads();
    #pragma unroll
    for (int k0=0; k0<64; k0+=32){
      int arow = wave*16 + l15;
      int ak = k0 + lhi*8;
      bf16x8 af = *(const bf16x8*)((const char*)lA + arow*128 + ((ak*2) ^ ((arow&7)<<4)));
      #pragma unroll
      for (int ct=0; ct<8; ++ct){
        int bn = ct*16 + l15;
        bf16x8 bfv = *(const bf16x8*)((const char*)lB + bn*128 + ((ak*2) ^ ((bn&7)<<4)));
        acc[ct] = __builtin_amdgcn_mfma_f32_16x16x32_bf16(af, bfv, acc[ct], 0, 0, 0);
      }
    }
    __syncthreads();
  }
  // epilogue: (acc + B_b) * dt  -> Bu fp32
  #pragma unroll
  for (int ct=0; ct<8; ++ct){
    int n = ct*16 + l15;
    float dt = fminf(__expf(logdt[n]), 1.f);
    float bb = Bb[n];
    #pragma unroll
    for (int r=0;r<4;++r){
      int m = m0 + wave*16 + lhi*4 + r;
      Bu[(size_t)m*128 + n] = (acc[ct][r] + bb) * dt;
    }
  }
}

// ---------------------------------------------------------------------------
// Scan: h[t] = A_bar*h[t-1] + Bu[t], chunked (A_bar const per channel so the
// chunk carry multiplier is just A_bar^CHUNK).
// ---------------------------------------------------------------------------
__global__ __launch_bounds__(128) void k_scan_carry(const float* __restrict__ Bu,
                                                    float* __restrict__ carry,
                                                    const float* __restrict__ logA,
                                                    const float* __restrict__ logdt){
  int n = threadIdx.x;
  float dt = fminf(__expf(logdt[n]), 1.f);
  float Ab = __expf(-__expf(logA[n]) * dt);
  const float* p = Bu + (size_t)blockIdx.x*CHUNK*128 + n;
  float h = 0.f;
  #pragma unroll 8
  for (int j=0;j<CHUNK;++j) h = fmaf(Ab, h, p[(size_t)j*128]);
  carry[(size_t)blockIdx.x*128 + n] = h;
}

__global__ __launch_bounds__(128) void k_scan_pref(const float* __restrict__ carry,
                                                   const float* __restrict__ h0,
                                                   float* __restrict__ hin,
                                                   const float* __restrict__ logA,
                                                   const float* __restrict__ logdt){
  int b = blockIdx.x;
  int n = threadIdx.x;
  float dt = fminf(__expf(logdt[n]), 1.f);
  float Ad = -__expf(logA[n]) * dt;
  float AL = __expf(Ad * (float)CHUNK);
  float h = h0[b*128 + n];
  hin[(size_t)(b*NCHUNK)*128 + n] = h;
  #pragma unroll 8
  for (int c=1;c<NCHUNK;++c){
    h = fmaf(AL, h, carry[(size_t)(b*NCHUNK + c - 1)*128 + n]);
    hin[(size_t)(b*NCHUNK + c)*128 + n] = h;
  }
}

// writes hs as bf16, pre-swizzled [mchunk 512][mm 64][k=n 128] so GEMM2's
// A-tile is a contiguous global_load_lds image.
__global__ __launch_bounds__(128) void k_scan_out(const float* __restrict__ Bu,
                                                  const float* __restrict__ hin,
                                                  unsigned short* __restrict__ hs,
                                                  const float* __restrict__ logA,
                                                  const float* __restrict__ logdt){
  int bc = blockIdx.x;           // = b*64 + c ; also the 64-row m-chunk index
  int n = threadIdx.x;
  float dt = fminf(__expf(logdt[n]), 1.f);
  float Ab = __expf(-__expf(logA[n]) * dt);
  float h = hin[(size_t)bc*128 + n];
  const float* p = Bu + (size_t)bc*CHUNK*128 + n;
  unsigned base = (unsigned)bc*16384u;
  #pragma unroll 4
  for (int j=0;j<CHUNK;++j){
    h = fmaf(Ab, h, p[(size_t)j*128]);
    unsigned byte = base + (unsigned)j*256u + (unsigned)((n*2) ^ ((j&15)<<4));
    hs[byte>>1] = f2bf(h);
  }
}

// ---------------------------------------------------------------------------
// GEMM2: y[m][d] = sum_n hs[m][n]*C_w[d][n] + C_b[d] + D_param[d]*u[m][d]
// M=32768 (BM=64), N=1024 (BN=128), K=128 (single pass)
// ---------------------------------------------------------------------------
__global__ __launch_bounds__(256) void k_gemm2(const unsigned short* __restrict__ hs,
                                               const unsigned short* __restrict__ cw,
                                               const float* __restrict__ u,
                                               const float* __restrict__ Cb,
                                               const float* __restrict__ Dp,
                                               float* __restrict__ y){
  __shared__ __align__(16) unsigned short lA[64*128];    // 16 KB
  __shared__ __align__(16) unsigned short lB[128*128];   // 32 KB
  const int tid = threadIdx.x, lane = tid & 63, wave = tid >> 6;
  const int bm = blockIdx.x & 511;
  const int bd = blockIdx.x >> 9;
  const int m0 = bm*64, d0 = bd*128;
  const int l15 = lane & 15, lhi = lane >> 4;

  #pragma unroll
  for (int rep=0; rep<4; ++rep){
    const char* g = (const char*)hs + bm*16384 + rep*4096 + wave*1024 + lane*16;
    char* l = (char*)lA + rep*4096 + wave*1024;
    cp16(g, l);
  }
  #pragma unroll
  for (int rep=0; rep<8; ++rep){
    const char* g = (const char*)cw + bd*32768 + rep*4096 + wave*1024 + lane*16;
    char* l = (char*)lB + rep*4096 + wave*1024;
    cp16(g, l);
  }

  f32x4 acc[8];
  #pragma unroll
  for (int i=0;i<8;++i) acc[i] = zero4();

  __syncthreads();

  #pragma unroll
  for (int k0=0;k0<128;k0+=32){
    int arow = wave*16 + l15;
    int ak = k0 + lhi*8;
    bf16x8 af = *(const bf16x8*)((const char*)lA + arow*256 + ((ak*2) ^ ((arow&15)<<4)));
    #pragma unroll
    for (int ct=0;ct<8;++ct){
      int dn = ct*16 + l15;
      bf16x8 bfv = *(const bf16x8*)((const char*)lB + dn*256 + ((ak*2) ^ ((dn&15)<<4)));
      acc[ct] = __builtin_amdgcn_mfma_f32_16x16x32_bf16(af, bfv, acc[ct], 0, 0, 0);
    }
  }

  #pragma unroll
  for (int ct=0;ct<8;++ct){
    int d = d0 + ct*16 + l15;
    float cb = Cb[d], dp = Dp[d];
    #pragma unroll
    for (int r=0;r<4;++r){
      int m = m0 + wave*16 + lhi*4 + r;
      size_t off = (size_t)m*1024 + d;
      y[off] = acc[ct][r] + cb + dp*u[off];
    }
  }
}

// ---------------------------------------------------------------------------
extern "C" void kernel_launch(void* const* d_in, const int* in_sizes, int n_in,
                              void* d_out, int out_size, void* d_ws, size_t ws_size,
                              hipStream_t stream){
  (void)in_sizes; (void)n_in; (void)out_size; (void)ws_size;
  const float* u     = (const float*)d_in[0];
  const float* h0    = (const float*)d_in[1];
  const float* logA  = (const float*)d_in[2];
  const float* Bw    = (const float*)d_in[3];
  const float* Bb    = (const float*)d_in[4];
  const float* Cw    = (const float*)d_in[5];
  const float* Cb    = (const float*)d_in[6];
  const float* Dp    = (const float*)d_in[7];
  const float* logdt = (const float*)d_in[8];
  float* y = (float*)d_out;

  char* ws = (char*)d_ws;
  float*          Bu    = (float*)(ws);                      // 16,777,216 B
  unsigned short* hsb   = (unsigned short*)(ws + 16777216);  //  8,388,608 B
  float*          carry = (float*)(ws + 25165824);           //    262,144 B
  float*          hin   = (float*)(ws + 25427968);           //    262,144 B
  unsigned short* bw    = (unsigned short*)(ws + 25690112);  //    262,144 B
  unsigned short* cw    = (unsigned short*)(ws + 25952256);  //    262,144 B
  // total ws use: 26,214,400 B

  k_conv      <<<dim3(512),  dim3(256), 0, stream>>>(Bw, Cw, bw, cw);
  k_gemm1     <<<dim3(512),  dim3(256), 0, stream>>>(u, bw, Bb, logdt, Bu);
  k_scan_carry<<<dim3(512),  dim3(128), 0, stream>>>(Bu, carry, logA, logdt);
  k_scan_pref <<<dim3(8),    dim3(128), 0, stream>>>(carry, h0, hin, logA, logdt);
  k_scan_out  <<<dim3(512),  dim3(128), 0, stream>>>(Bu, hin, hsb, logA, logdt);
  k_gemm2     <<<dim3(4096), dim3(256), 0, stream>>>(hsb, cw, u, Cb, Dp, y);
}

// Round 2
// 91.604 us; speedup vs baseline: 1.1626x; 1.1626x over previous
//
#include <hip/hip_runtime.h>

#define B_SZ 8
#define T_SZ 4096
#define D_SZ 1024
#define N_SZ 128
#define M_SZ (B_SZ*T_SZ)          // 32768
#define CHUNK 64                  // scan chunk length
#define NCHUNK (T_SZ/CHUNK)       // 64

typedef __attribute__((ext_vector_type(8))) __bf16 bf16x8;
typedef __attribute__((ext_vector_type(4))) float f32x4;
typedef __attribute__((ext_vector_type(4))) unsigned int u32x4;
typedef __attribute__((ext_vector_type(4))) float fvec4;

static __device__ __forceinline__ unsigned short f2bf(float f){
  union { float f; unsigned int u; } v; v.f = f;
  unsigned int r = v.u + 0x7fffu + ((v.u >> 16) & 1u);
  return (unsigned short)(r >> 16);
}

static __device__ __forceinline__ void cp16(const void* g, void* l){
  __builtin_amdgcn_global_load_lds(
      (const __attribute__((address_space(1))) void*)g,
      (__attribute__((address_space(3))) void*)l, 16, 0, 0);
}

static __device__ __forceinline__ f32x4 zero4(){
  f32x4 v = {0.f, 0.f, 0.f, 0.f};
  return v;
}

// ---------------------------------------------------------------------------
// K0: convert weights to bf16, pre-swizzled so GEMM tiles are contiguous
// global_load_lds images.
// bw: [16 kchunks][128 n][64 k] bf16; byte = c*16384 + n*128 + ((kk*2)^((n&7)<<4))
// cw: [8 dchunks][128 d][128 k] bf16; byte = c*32768 + dd*256 + ((k*2)^((dd&15)<<4))
// ---------------------------------------------------------------------------
__global__ __launch_bounds__(256) void k_conv(const float* __restrict__ Bw,
                                              const float* __restrict__ Cw,
                                              unsigned short* __restrict__ bw,
                                              unsigned short* __restrict__ cw){
  int t = blockIdx.x*256 + threadIdx.x;   // 131072 threads total
  {
    int n = t >> 10, k = t & 1023;
    int c = k >> 6, kk = k & 63;
    unsigned byte = (unsigned)c*16384u + (unsigned)n*128u
                  + (unsigned)((kk*2) ^ ((n&7)<<4));
    bw[byte>>1] = f2bf(Bw[n*1024 + k]);
  }
  {
    int d = t >> 7, k = t & 127;
    int c = d >> 7, dd = d & 127;
    unsigned byte = (unsigned)c*32768u + (unsigned)dd*256u
                  + (unsigned)((k*2) ^ ((dd&15)<<4));
    cw[byte>>1] = f2bf(Cw[d*128 + k]);
  }
}

// ---------------------------------------------------------------------------
// GEMM1 + chunk-local scan carry (fused):
//   Bu[m][n] = (sum_k u[m][k]*B_w[n][k] + B_b[n]) * dt[n]
//   carry[chunk][n] = local scan of the 64-row chunk starting from h=0
// One block = one 64-row m-chunk = exactly one scan chunk.
// ---------------------------------------------------------------------------
__global__ __launch_bounds__(256) void k_gemm1c(const float* __restrict__ u,
                                                const unsigned short* __restrict__ bw,
                                                const float* __restrict__ Bb,
                                                const float* __restrict__ logA,
                                                const float* __restrict__ logdt,
                                                float* __restrict__ Bu,
                                                float* __restrict__ carry){
  __shared__ __align__(16) char smem[32768];
  unsigned short* lA = (unsigned short*)smem;           //  8 KB during GEMM
  unsigned short* lB = (unsigned short*)(smem + 8192);  // 16 KB during GEMM
  float*          BuT = (float*)smem;                   // 32 KB after GEMM
  const int tid  = threadIdx.x;
  const int lane = tid & 63;
  const int wave = tid >> 6;
  const int bc   = blockIdx.x;
  const int m0   = bc * 64;
  const int l15  = lane & 15;
  const int lhi  = lane >> 4;

  f32x4 acc[8];
  #pragma unroll
  for (int i=0;i<8;++i) acc[i] = zero4();

  for (int kc=0; kc<16; ++kc){
    // stage B_w k-chunk: 16KB contiguous (pre-swizzled) via global_load_lds
    #pragma unroll
    for (int rep=0; rep<4; ++rep){
      const char* g = (const char*)bw + kc*16384 + rep*4096 + wave*1024 + lane*16;
      char* l = (char*)lB + rep*4096 + wave*1024;
      cp16(g, l);
    }
    // stage u tile: fp32 -> bf16, swizzled ds_write
    #pragma unroll
    for (int rep=0; rep<2; ++rep){
      int q = rep*256 + tid;            // 0..511
      int row = q >> 3, ks = q & 7;
      const float* src = u + (size_t)(m0+row)*1024 + kc*64 + ks*8;
      fvec4 f0 = *(const fvec4*)src;
      fvec4 f1 = *(const fvec4*)(src+4);
      u32x4 p;
      p.x = (unsigned)f2bf(f0.x) | ((unsigned)f2bf(f0.y)<<16);
      p.y = (unsigned)f2bf(f0.z) | ((unsigned)f2bf(f0.w)<<16);
      p.z = (unsigned)f2bf(f1.x) | ((unsigned)f2bf(f1.y)<<16);
      p.w = (unsigned)f2bf(f1.z) | ((unsigned)f2bf(f1.w)<<16);
      unsigned byte = (unsigned)row*128u + (unsigned)((ks*16) ^ ((row&7)<<4));
      *(u32x4*)((char*)lA + byte) = p;
    }
    __syncthreads();
    #pragma unroll
    for (int k0=0; k0<64; k0+=32){
      int arow = wave*16 + l15;
      int ak = k0 + lhi*8;
      bf16x8 af = *(const bf16x8*)((const char*)lA + arow*128 + ((ak*2) ^ ((arow&7)<<4)));
      #pragma unroll
      for (int ct=0; ct<8; ++ct){
        int bn = ct*16 + l15;
        bf16x8 bfv = *(const bf16x8*)((const char*)lB + bn*128 + ((ak*2) ^ ((bn&7)<<4)));
        acc[ct] = __builtin_amdgcn_mfma_f32_16x16x32_bf16(af, bfv, acc[ct], 0, 0, 0);
      }
    }
    __syncthreads();
  }

  // epilogue: buv = (acc + B_b)*dt -> LDS tile (overwrites lA/lB, safe after sync)
  #pragma unroll
  for (int ct=0; ct<8; ++ct){
    int n = ct*16 + l15;
    float dt = fminf(__expf(logdt[n]), 1.f);
    float bb = Bb[n];
    #pragma unroll
    for (int r=0;r<4;++r){
      int ml = wave*16 + lhi*4 + r;
      BuT[ml*128 + n] = (acc[ct][r] + bb) * dt;
    }
  }
  __syncthreads();

  // coalesced float4 write of the Bu tile to global
  fvec4* dst = (fvec4*)(Bu + (size_t)bc*64*128);
  const fvec4* srcT = (const fvec4*)BuT;
  #pragma unroll
  for (int i=0;i<8;++i){
    int idx = i*256 + tid;            // 2048 float4s = 32 KB
    dst[idx] = srcT[idx];
  }

  // chunk-local scan carry (h starts at 0)
  if (tid < 128){
    int n = tid;
    float dt = fminf(__expf(logdt[n]), 1.f);
    float Ab = __expf(-__expf(logA[n]) * dt);
    float h = 0.f;
    #pragma unroll 8
    for (int j=0;j<CHUNK;++j) h = fmaf(Ab, h, BuT[j*128 + n]);
    carry[(size_t)bc*128 + n] = h;
  }
}

// ---------------------------------------------------------------------------
// Cross-chunk prefix: hin[b,c] = state entering chunk c of batch b.
// ---------------------------------------------------------------------------
__global__ __launch_bounds__(128) void k_scan_pref(const float* __restrict__ carry,
                                                   const float* __restrict__ h0,
                                                   float* __restrict__ hin,
                                                   const float* __restrict__ logA,
                                                   const float* __restrict__ logdt){
  int b = blockIdx.x;
  int n = threadIdx.x;
  float dt = fminf(__expf(logdt[n]), 1.f);
  float Ad = -__expf(logA[n]) * dt;
  float AL = __expf(Ad * (float)CHUNK);
  float h = h0[b*128 + n];
  hin[(size_t)(b*NCHUNK)*128 + n] = h;
  #pragma unroll 8
  for (int c=1;c<NCHUNK;++c){
    h = fmaf(AL, h, carry[(size_t)(b*NCHUNK + c - 1)*128 + n]);
    hin[(size_t)(b*NCHUNK + c)*128 + n] = h;
  }
}

// ---------------------------------------------------------------------------
// GEMM2 + scan_out (fused): one block per 64-row m-chunk.
//   - load Bu tile (32KB) -> LDS (waves 0,1) ; load cw chunk0 (32KB) (waves 2,3)
//   - 128 threads run the 64-step local scan from hin, writing swizzled bf16 hs
//   - loop d-chunks 0..7: MFMA (64x128 x 128x128) + epilogue y = acc+Cb+Dp*u
// ---------------------------------------------------------------------------
__global__ __launch_bounds__(256) void k_gemm2s(const float* __restrict__ Bu,
                                                const float* __restrict__ hin,
                                                const unsigned short* __restrict__ cw,
                                                const float* __restrict__ u,
                                                const float* __restrict__ Cb,
                                                const float* __restrict__ Dp,
                                                const float* __restrict__ logA,
                                                const float* __restrict__ logdt,
                                                float* __restrict__ y){
  __shared__ __align__(16) float          BuT[64*128];      // 32 KB
  __shared__ __align__(16) unsigned short hsT[64*128];      // 16 KB swizzled
  __shared__ __align__(16) unsigned short cwT[128*128];     // 32 KB swizzled
  const int tid = threadIdx.x, lane = tid & 63, wave = tid >> 6;
  const int bc = blockIdx.x;
  const int m0 = bc * 64;
  const int l15 = lane & 15, lhi = lane >> 4;

  // stage: waves 0,1 -> Bu tile (32 wave-instrs total); waves 2,3 -> cw chunk 0
  if (wave < 2){
    #pragma unroll
    for (int i=0;i<16;++i){
      int off = (wave*16 + i)*1024 + lane*16;
      cp16((const char*)Bu + (size_t)bc*32768 + off, (char*)BuT + off);
    }
  } else {
    #pragma unroll
    for (int i=0;i<16;++i){
      int off = ((wave-2)*16 + i)*1024 + lane*16;
      cp16((const char*)cw + off, (char*)cwT + off);
    }
  }
  __syncthreads();

  // local scan -> swizzled bf16 hs image
  if (tid < 128){
    int n = tid;
    float dt = fminf(__expf(logdt[n]), 1.f);
    float Ab = __expf(-__expf(logA[n]) * dt);
    float h = hin[(size_t)bc*128 + n];
    #pragma unroll 8
    for (int j=0;j<CHUNK;++j){
      h = fmaf(Ab, h, BuT[j*128 + n]);
      unsigned byte = (unsigned)j*256u + (unsigned)((n*2) ^ ((j&15)<<4));
      *(unsigned short*)((char*)hsT + byte) = f2bf(h);
    }
  }
  __syncthreads();

  for (int d=0; d<8; ++d){
    f32x4 acc[8];
    #pragma unroll
    for (int i=0;i<8;++i) acc[i] = zero4();

    #pragma unroll
    for (int k0=0;k0<128;k0+=32){
      int arow = wave*16 + l15;
      int ak = k0 + lhi*8;
      bf16x8 af = *(const bf16x8*)((const char*)hsT + arow*256 + ((ak*2) ^ ((arow&15)<<4)));
      #pragma unroll
      for (int ct=0;ct<8;++ct){
        int dn = ct*16 + l15;
        bf16x8 bfv = *(const bf16x8*)((const char*)cwT + dn*256 + ((ak*2) ^ ((dn&15)<<4)));
        acc[ct] = __builtin_amdgcn_mfma_f32_16x16x32_bf16(af, bfv, acc[ct], 0, 0, 0);
      }
    }
    __syncthreads();              // all waves done reading cwT

    if (d < 7){                   // stage next cw chunk (all 4 waves)
      #pragma unroll
      for (int i=0;i<8;++i){
        int off = (wave*8 + i)*1024 + lane*16;
        cp16((const char*)cw + (size_t)(d+1)*32768 + off, (char*)cwT + off);
      }
    }

    // epilogue: y = acc + Cb + Dp*u  (fp32)
    const int d0 = d*128;
    #pragma unroll
    for (int ct=0;ct<8;++ct){
      int dc = d0 + ct*16 + l15;
      float cb = Cb[dc], dp = Dp[dc];
      #pragma unroll
      for (int r=0;r<4;++r){
        int m = m0 + wave*16 + lhi*4 + r;
        size_t off = (size_t)m*1024 + dc;
        y[off] = acc[ct][r] + cb + dp*u[off];
      }
    }
    __syncthreads();              // staging (and reads) settled before next MFMA
  }
}

// ---------------------------------------------------------------------------
extern "C" void kernel_launch(void* const* d_in, const int* in_sizes, int n_in,
                              void* d_out, int out_size, void* d_ws, size_t ws_size,
                              hipStream_t stream){
  (void)in_sizes; (void)n_in; (void)out_size; (void)ws_size;
  const float* u     = (const float*)d_in[0];
  const float* h0    = (const float*)d_in[1];
  const float* logA  = (const float*)d_in[2];
  const float* Bw    = (const float*)d_in[3];
  const float* Bb    = (const float*)d_in[4];
  const float* Cw    = (const float*)d_in[5];
  const float* Cb    = (const float*)d_in[6];
  const float* Dp    = (const float*)d_in[7];
  const float* logdt = (const float*)d_in[8];
  float* y = (float*)d_out;

  char* ws = (char*)d_ws;
  float*          Bu    = (float*)(ws);                      // 16,777,216 B
  float*          carry = (float*)(ws + 16777216);           //    262,144 B
  float*          hin   = (float*)(ws + 17039360);           //    262,144 B
  unsigned short* bw    = (unsigned short*)(ws + 17301504);  //    262,144 B
  unsigned short* cw    = (unsigned short*)(ws + 17563648);  //    262,144 B
  // total ws use: 17,825,792 B

  k_conv      <<<dim3(512), dim3(256), 0, stream>>>(Bw, Cw, bw, cw);
  k_gemm1c    <<<dim3(512), dim3(256), 0, stream>>>(u, bw, Bb, logA, logdt, Bu, carry);
  k_scan_pref <<<dim3(8),   dim3(128), 0, stream>>>(carry, h0, hin, logA, logdt);
  k_gemm2s    <<<dim3(512), dim3(256), 0, stream>>>(Bu, hin, cw, u, Cb, Dp, logA, logdt, y);
}

// Round 4
// 87.882 us; speedup vs baseline: 1.2118x; 1.0423x over previous
//
#include <hip/hip_runtime.h>

#define B_SZ 8
#define T_SZ 4096
#define D_SZ 1024
#define N_SZ 128
#define M_SZ (B_SZ*T_SZ)          // 32768
#define CHUNK 64                  // scan chunk length = GEMM tile rows
#define NCHUNK (T_SZ/CHUNK)       // 64 chunks per batch

typedef __attribute__((ext_vector_type(8))) __bf16 bf16x8;
typedef __attribute__((ext_vector_type(4))) float f32x4;
typedef __attribute__((ext_vector_type(4))) unsigned int u32x4;
typedef __attribute__((ext_vector_type(4))) float fvec4;

static __device__ __forceinline__ unsigned short f2bf(float f){
  union { float f; unsigned int u; } v; v.f = f;
  unsigned int r = v.u + 0x7fffu + ((v.u >> 16) & 1u);
  return (unsigned short)(r >> 16);
}

static __device__ __forceinline__ float bf2f(unsigned short s){
  union { unsigned int u; float f; } v; v.u = ((unsigned)s) << 16;
  return v.f;
}

static __device__ __forceinline__ void cp16(const void* g, void* l){
  __builtin_amdgcn_global_load_lds(
      (const __attribute__((address_space(1))) void*)g,
      (__attribute__((address_space(3))) void*)l, 16, 0, 0);
}

static __device__ __forceinline__ f32x4 zero4(){
  f32x4 v = {0.f, 0.f, 0.f, 0.f};
  return v;
}

// ---------------------------------------------------------------------------
// K0: convert weights to bf16, pre-swizzled so GEMM tiles are contiguous
// global_load_lds images.
// bw: [16 kchunks][128 n][64 k] bf16; byte = c*16384 + n*128 + ((kk*2)^((n&7)<<4))
// cw: [8 dchunks][128 d][128 k] bf16; byte = c*32768 + dd*256 + ((k*2)^((dd&15)<<4))
// ---------------------------------------------------------------------------
__global__ __launch_bounds__(256) void k_conv(const float* __restrict__ Bw,
                                              const float* __restrict__ Cw,
                                              unsigned short* __restrict__ bw,
                                              unsigned short* __restrict__ cw){
  int t = blockIdx.x*256 + threadIdx.x;   // 131072 threads total
  {
    int n = t >> 10, k = t & 1023;
    int c = k >> 6, kk = k & 63;
    unsigned byte = (unsigned)c*16384u + (unsigned)n*128u
                  + (unsigned)((kk*2) ^ ((n&7)<<4));
    bw[byte>>1] = f2bf(Bw[n*1024 + k]);
  }
  {
    int d = t >> 7, k = t & 127;
    int c = d >> 7, dd = d & 127;
    unsigned byte = (unsigned)c*32768u + (unsigned)dd*256u
                  + (unsigned)((k*2) ^ ((dd&15)<<4));
    cw[byte>>1] = f2bf(Cw[d*128 + k]);
  }
}

// ---------------------------------------------------------------------------
// GEMM1 + chunk-local scan carry (fused):
//   Bu[m][n] = (sum_k u[m][k]*B_w[n][k] + B_b[n]) * dt[n]  -> bf16 to global
//   carry[chunk][n] = local scan of the 64-row chunk starting from h=0 (fp32)
// One block = one 64-row m-chunk = exactly one scan chunk.
// ---------------------------------------------------------------------------
__global__ __launch_bounds__(256) void k_gemm1c(const float* __restrict__ u,
                                                const unsigned short* __restrict__ bw,
                                                const float* __restrict__ Bb,
                                                const float* __restrict__ logA,
                                                const float* __restrict__ logdt,
                                                unsigned short* __restrict__ Bu_bf,
                                                float* __restrict__ carry){
  __shared__ __align__(16) char smem[32768];
  unsigned short* lA = (unsigned short*)smem;           //  8 KB during GEMM
  unsigned short* lB = (unsigned short*)(smem + 8192);  // 16 KB during GEMM
  float*          BuT = (float*)smem;                   // 32 KB after GEMM
  const int tid  = threadIdx.x;
  const int lane = tid & 63;
  const int wave = tid >> 6;
  const int bc   = blockIdx.x;
  const int m0   = bc * 64;
  const int l15  = lane & 15;
  const int lhi  = lane >> 4;

  f32x4 acc[8];
  #pragma unroll
  for (int i=0;i<8;++i) acc[i] = zero4();

  for (int kc=0; kc<16; ++kc){
    // stage B_w k-chunk: 16KB contiguous (pre-swizzled) via global_load_lds
    #pragma unroll
    for (int rep=0; rep<4; ++rep){
      const char* g = (const char*)bw + kc*16384 + rep*4096 + wave*1024 + lane*16;
      char* l = (char*)lB + rep*4096 + wave*1024;
      cp16(g, l);
    }
    // stage u tile: fp32 -> bf16, swizzled ds_write
    #pragma unroll
    for (int rep=0; rep<2; ++rep){
      int q = rep*256 + tid;            // 0..511
      int row = q >> 3, ks = q & 7;
      const float* src = u + (size_t)(m0+row)*1024 + kc*64 + ks*8;
      fvec4 f0 = *(const fvec4*)src;
      fvec4 f1 = *(const fvec4*)(src+4);
      u32x4 p;
      p.x = (unsigned)f2bf(f0.x) | ((unsigned)f2bf(f0.y)<<16);
      p.y = (unsigned)f2bf(f0.z) | ((unsigned)f2bf(f0.w)<<16);
      p.z = (unsigned)f2bf(f1.x) | ((unsigned)f2bf(f1.y)<<16);
      p.w = (unsigned)f2bf(f1.z) | ((unsigned)f2bf(f1.w)<<16);
      unsigned byte = (unsigned)row*128u + (unsigned)((ks*16) ^ ((row&7)<<4));
      *(u32x4*)((char*)lA + byte) = p;
    }
    __syncthreads();
    #pragma unroll
    for (int k0=0; k0<64; k0+=32){
      int arow = wave*16 + l15;
      int ak = k0 + lhi*8;
      bf16x8 af = *(const bf16x8*)((const char*)lA + arow*128 + ((ak*2) ^ ((arow&7)<<4)));
      #pragma unroll
      for (int ct=0; ct<8; ++ct){
        int bn = ct*16 + l15;
        bf16x8 bfv = *(const bf16x8*)((const char*)lB + bn*128 + ((ak*2) ^ ((bn&7)<<4)));
        acc[ct] = __builtin_amdgcn_mfma_f32_16x16x32_bf16(af, bfv, acc[ct], 0, 0, 0);
      }
    }
    __syncthreads();
  }

  // epilogue: (acc + B_b)*dt -> LDS tile fp32 (overwrites lA/lB, safe after sync)
  #pragma unroll
  for (int ct=0; ct<8; ++ct){
    int n = ct*16 + l15;
    float dt = fminf(__expf(logdt[n]), 1.f);
    float bb = Bb[n];
    #pragma unroll
    for (int r=0;r<4;++r){
      int ml = wave*16 + lhi*4 + r;
      BuT[ml*128 + n] = (acc[ct][r] + bb) * dt;
    }
  }
  __syncthreads();

  // pack Bu tile to bf16, coalesced 16B stores (1024 items of 8 elems)
  #pragma unroll
  for (int i=0;i<4;++i){
    int q = i*256 + tid;
    const float* s = BuT + q*8;
    fvec4 a = *(const fvec4*)s;
    fvec4 b = *(const fvec4*)(s+4);
    u32x4 p;
    p.x = (unsigned)f2bf(a.x) | ((unsigned)f2bf(a.y)<<16);
    p.y = (unsigned)f2bf(a.z) | ((unsigned)f2bf(a.w)<<16);
    p.z = (unsigned)f2bf(b.x) | ((unsigned)f2bf(b.y)<<16);
    p.w = (unsigned)f2bf(b.z) | ((unsigned)f2bf(b.w)<<16);
    *(u32x4*)((char*)Bu_bf + (size_t)bc*16384 + (size_t)q*16) = p;
  }

  // chunk-local scan carry (h starts at 0), fp32 from LDS
  if (tid < 128){
    int n = tid;
    float dt = fminf(__expf(logdt[n]), 1.f);
    float Ab = __expf(-__expf(logA[n]) * dt);
    float h = 0.f;
    #pragma unroll 8
    for (int j=0;j<CHUNK;++j) h = fmaf(Ab, h, BuT[j*128 + n]);
    carry[(size_t)bc*128 + n] = h;
  }
}

// ---------------------------------------------------------------------------
// GEMM2 + prefix + scan (fused): one block per 64-row m-chunk.
//   - stage Bu bf16 tile (16KB) + cw chunk0 (32KB) via global_load_lds
//   - meanwhile compute cross-chunk prefix h from carry[] (registers)
//   - 128 threads: 64-step local scan -> swizzled bf16 hsT
//   - loop d-chunks 0..7: MFMA (64x128 x 128x128) + epilogue y = acc+Cb+Dp*u
// ---------------------------------------------------------------------------
__global__ __launch_bounds__(256) void k_gemm2s(const unsigned short* __restrict__ Bu_bf,
                                                const float* __restrict__ carry,
                                                const unsigned short* __restrict__ cw,
                                                const float* __restrict__ u,
                                                const float* __restrict__ h0,
                                                const float* __restrict__ Cb,
                                                const float* __restrict__ Dp,
                                                const float* __restrict__ logA,
                                                const float* __restrict__ logdt,
                                                float* __restrict__ y){
  __shared__ __align__(16) unsigned short BuT[64*128];      // 16 KB bf16 linear
  __shared__ __align__(16) unsigned short hsT[64*128];      // 16 KB swizzled
  __shared__ __align__(16) unsigned short cwT[128*128];     // 32 KB swizzled
  const int tid = threadIdx.x, lane = tid & 63, wave = tid >> 6;
  const int bc = blockIdx.x;
  const int m0 = bc * 64;
  const int l15 = lane & 15, lhi = lane >> 4;

  // stage Bu tile (4 rounds) + cw chunk 0 (8 rounds); async, drained at barrier
  #pragma unroll
  for (int i=0;i<4;++i){
    int off = i*4096 + tid*16;
    cp16((const char*)Bu_bf + (size_t)bc*16384 + off, (char*)BuT + off);
  }
  #pragma unroll
  for (int i=0;i<8;++i){
    int off = i*4096 + tid*16;
    cp16((const char*)cw + off, (char*)cwT + off);
  }

  // cross-chunk prefix in registers (overlaps with the staging above)
  float hreg = 0.f, Ab = 0.f;
  if (tid < 128){
    int n = tid;
    int b = bc >> 6, c = bc & 63;
    float dt = fminf(__expf(logdt[n]), 1.f);
    float Ad = -__expf(logA[n]) * dt;
    Ab = __expf(Ad);
    float AL = __expf(Ad * (float)CHUNK);
    float h = h0[b*128 + n];
    for (int i=0;i<c;++i)
      h = fmaf(AL, h, carry[(size_t)(b*NCHUNK + i)*128 + n]);
    hreg = h;
  }
  __syncthreads();

  // local scan (bf16 Bu from LDS) -> swizzled bf16 hsT
  if (tid < 128){
    int n = tid;
    float h = hreg;
    #pragma unroll 8
    for (int j=0;j<CHUNK;++j){
      h = fmaf(Ab, h, bf2f(BuT[j*128 + n]));
      unsigned byte = (unsigned)j*256u + (unsigned)((n*2) ^ ((j&15)<<4));
      *(unsigned short*)((char*)hsT + byte) = f2bf(h);
    }
  }
  __syncthreads();

  for (int d=0; d<8; ++d){
    f32x4 acc[8];
    #pragma unroll
    for (int i=0;i<8;++i) acc[i] = zero4();

    #pragma unroll
    for (int k0=0;k0<128;k0+=32){
      int arow = wave*16 + l15;
      int ak = k0 + lhi*8;
      bf16x8 af = *(const bf16x8*)((const char*)hsT + arow*256 + ((ak*2) ^ ((arow&15)<<4)));
      #pragma unroll
      for (int ct=0;ct<8;++ct){
        int dn = ct*16 + l15;
        bf16x8 bfv = *(const bf16x8*)((const char*)cwT + dn*256 + ((ak*2) ^ ((dn&15)<<4)));
        acc[ct] = __builtin_amdgcn_mfma_f32_16x16x32_bf16(af, bfv, acc[ct], 0, 0, 0);
      }
    }
    __syncthreads();              // all waves done reading cwT

    if (d < 7){                   // stage next cw chunk (async)
      #pragma unroll
      for (int i=0;i<8;++i){
        int off = (wave*8 + i)*1024 + lane*16;
        cp16((const char*)cw + (size_t)(d+1)*32768 + off, (char*)cwT + off);
      }
    }

    // epilogue: y = acc + Cb + Dp*u  (overlaps the async staging)
    const int d0 = d*128;
    #pragma unroll
    for (int ct=0;ct<8;++ct){
      int dc = d0 + ct*16 + l15;
      float cb = Cb[dc], dp = Dp[dc];
      #pragma unroll
      for (int r=0;r<4;++r){
        int m = m0 + wave*16 + lhi*4 + r;
        size_t off = (size_t)m*1024 + dc;
        y[off] = acc[ct][r] + cb + dp*u[off];
      }
    }
    __syncthreads();              // drains cp16s before next MFMA
  }
}

// ---------------------------------------------------------------------------
extern "C" void kernel_launch(void* const* d_in, const int* in_sizes, int n_in,
                              void* d_out, int out_size, void* d_ws, size_t ws_size,
                              hipStream_t stream){
  (void)in_sizes; (void)n_in; (void)out_size; (void)ws_size;
  const float* u     = (const float*)d_in[0];
  const float* h0    = (const float*)d_in[1];
  const float* logA  = (const float*)d_in[2];
  const float* Bw    = (const float*)d_in[3];
  const float* Bb    = (const float*)d_in[4];
  const float* Cw    = (const float*)d_in[5];
  const float* Cb    = (const float*)d_in[6];
  const float* Dp    = (const float*)d_in[7];
  const float* logdt = (const float*)d_in[8];
  float* y = (float*)d_out;

  char* ws = (char*)d_ws;
  unsigned short* Bu_bf = (unsigned short*)(ws);             // 8,388,608 B
  float*          carry = (float*)(ws + 8388608);            //   262,144 B
  unsigned short* bw    = (unsigned short*)(ws + 8650752);   //   262,144 B
  unsigned short* cw    = (unsigned short*)(ws + 8912896);   //   262,144 B
  // total ws use: 9,175,040 B

  k_conv  <<<dim3(512), dim3(256), 0, stream>>>(Bw, Cw, bw, cw);
  k_gemm1c<<<dim3(512), dim3(256), 0, stream>>>(u, bw, Bb, logA, logdt, Bu_bf, carry);
  k_gemm2s<<<dim3(512), dim3(256), 0, stream>>>(Bu_bf, carry, cw, u, h0, Cb, Dp,
                                                logA, logdt, y);
}